// Round 5
// baseline (2978.493 us; speedup 1.0000x reference)
//
#include <hip/hip_runtime.h>
#include <vector>
#include <cmath>
#include <cstdint>

// ---------------- static model tables (constexpr, device-usable) ----------------
constexpr int KLc[4]  = {256,192,128,64};     // k_max per l
constexpr int NMLc[4] = {8,6,4,2};            // radial basis per l
constexpr int SHBc[5] = {0,1,4,9,16};         // sh split bases
constexpr int RBBc[5] = {0,8,14,18,20};       // rb split bases
constexpr int FBc[5]  = {0,256,832,1472,1920};// feats flat base per l  (sum (2l+1)*K[l])
constexpr int NCMB = 34, CGTOT = 3436, FTOT = 1920;

struct Combos { int l1[NCMB], l2[NCMB], L[NCMB], cgoff[NCMB], kk[NCMB]; };
constexpr Combos make_combos(){
  Combos c{}; int n=0, cg=0;
  for(int a=0;a<=3;a++)for(int b=0;b<=3;b++){
    int lo=a>b?a-b:b-a, hi=(a+b<3)?(a+b):3;
    for(int L=lo;L<=hi;L++){
      c.l1[n]=a; c.l2[n]=b; c.L[n]=L; c.cgoff[n]=cg;
      int mx=a>b?a:b; if(L>mx) mx=L; c.kk[n]=KLc[mx];          // TP truncation (min of all three)
      cg+=(2*a+1)*(2*b+1)*(2*L+1); n++;
    }
  }
  return c;
}
constexpr Combos CB = make_combos();
static_assert(CB.cgoff[NCMB-1] + 7*7*7 == CGTOT, "cg size");

struct Grp { int cnt[4]; int list[4][12]; };
constexpr Grp make_Lg(){ Grp g{}; for(int i=0;i<NCMB;i++){ int L=CB.L[i]; g.list[L][g.cnt[L]++]=i; } return g; }
constexpr Grp LG = make_Lg();     // combos grouped by output L (for k_tp)

struct Rows { int sh[64], rb[64], off[64]; };
constexpr Rows make_rows(){ Rows r{}; int i=0;
  for(int l=0;l<4;l++)for(int m=0;m<2*l+1;m++)for(int n=0;n<NMLc[l];n++){
    r.sh[i]=SHBc[l]+m; r.rb[i]=RBBc[l]+n; r.off[i]=FBc[l]+m*KLc[l]+n*32; i++; }
  for(;i<64;i++){ r.sh[i]=0; r.rb[i]=0; r.off[i]=0; }
  return r; }
constexpr Rows RWS = make_rows();  // 60 (l,m,n) rows for invariant MP

// ---------------- k_eq tables: S-factorization slices, row-partitioned 8 wave-groups ----------------
// S[l1,a,l2,b][k] = sum_pairs edge[l1,a] * femb[l2,b,k]; slice unit = (l1,a,l2,b,ktile)
// Slice valid iff l2 <= 3-kt && |l1-l2| <= 3-kt   (equivariant kk = min(K[l2],K[L]), L>=|l1-l2|)
// Rows (l2,b,kt) are partitioned across groups (greedy) so each feature row is gathered ONCE.
constexpr int NSL=425, NG=8, MAXS=57, MAXR=4, RPAD=149; // RPAD odd -> 2-way bank aliasing (free)

constexpr int iabs_(int x){ return x<0?-x:x; }
__host__ __device__ constexpr bool sl_valid(int l1,int l2,int kt){ return l2<=3-kt && iabs_(l1-l2)<=3-kt; }

__host__ __device__ constexpr int rb_base(int kt,int l1,int l2){
  int base=0;
  for(int p=0;p<4;p++)for(int q=0;q<4;q++){
    if(p==l1 && q==l2) return base;
    if(sl_valid(p,q,kt)) base += (2*p+1)*(2*q+1);
  }
  return base;
}

struct EqTab {
  int ns[NG];
  unsigned char eidx[NG][MAXS];   // edge register index (SHB[l1]+a)
  unsigned char fidx[NG][MAXS];   // row index within group (0..NR-1)
  short         srow[NG][MAXS];   // stage row within its dump phase
  unsigned char sph [NG][MAXS];   // dump phase 0..4
  int nr[NG];
  short roff[NG][MAXR];           // feature row offsets into feats (element units)
  int total;
};
constexpr EqTab make_eqtab(){
  EqTab T{};
  int rl2[30], rbb[30], rkt[30], rsc[30]; int nrw=0;
  for(int l2=0;l2<4;l2++)for(int kt=0;kt<4-l2;kt++)for(int b=0;b<2*l2+1;b++){
    int sc=0; for(int l1=0;l1<4;l1++) if(sl_valid(l1,l2,kt)) sc+=2*l1+1;
    rl2[nrw]=l2; rbb[nrw]=b; rkt[nrw]=kt; rsc[nrw]=sc; nrw++;
  }
  bool used[30]={}; int load[NG]={};
  for(int it=0; it<nrw; it++){
    int best=-1,bsc=-1;
    for(int i=0;i<nrw;i++) if(!used[i] && rsc[i]>bsc){bsc=rsc[i];best=i;}
    used[best]=true;
    int g=0; for(int j=1;j<NG;j++) if(load[j]<load[g]) g=j;
    load[g]+=bsc;
    const int l2=rl2[best], b=rbb[best], kt=rkt[best];
    const int ri = T.nr[g];
    T.roff[g][T.nr[g]++] = (short)(FBc[l2]+b*KLc[l2]+kt*64);
    for(int l1=0;l1<4;l1++){
      if(!sl_valid(l1,l2,kt)) continue;
      for(int a=0;a<2*l1+1;a++){
        int s=T.ns[g]++;
        T.eidx[g][s]=(unsigned char)(SHBc[l1]+a);
        T.fidx[g][s]=(unsigned char)ri;
        int rbi = rb_base(kt,l1,l2)+a*(2*l2+1)+b;
        int ph,sr;
        if(kt==0){ if(l1<=2){ph=0;sr=rbi;} else {ph=1;sr=rbi-144;} }
        else {ph=kt+1;sr=rbi;}
        T.sph[g][s]=(unsigned char)ph; T.srow[g][s]=(short)sr;
        T.total++;
      }
    }
  }
  return T;
}
constexpr EqTab ET = make_eqtab();
static_assert(ET.total==NSL, "slice count");
constexpr bool chk_ns(){ for(int g=0;g<NG;g++) if(ET.ns[g]>MAXS) return false; return true; }
constexpr bool chk_nr(){ for(int g=0;g<NG;g++) if(ET.nr[g]>MAXR) return false; return true; }
static_assert(chk_ns(), "MAXS");
static_assert(chk_nr(), "MAXR");

// contraction combo -> group assignment (greedy by cost n1*n2*nL)
struct CAsg { int cnt[NG]; unsigned char ci[NG][8]; };
constexpr CAsg make_casg(){
  CAsg C{}; bool used[NCMB]{}; int load[NG]{};
  for(int it=0; it<NCMB; it++){
    int best=-1, bc=-1;
    for(int i=0;i<NCMB;i++) if(!used[i]){
      int c=(2*CB.l1[i]+1)*(2*CB.l2[i]+1)*(2*CB.L[i]+1);
      if(c>bc){bc=c;best=i;}
    }
    used[best]=true;
    int g=0; for(int j=1;j<NG;j++) if(load[j]<load[g]) g=j;
    C.ci[g][C.cnt[g]++]=(unsigned char)best; load[g]+=bc;
  }
  return C;
}
constexpr CAsg CA = make_casg();
constexpr bool chk_ca(){ for(int g=0;g<NG;g++) if(CA.cnt[g]>8) return false; return true; }
static_assert(chk_ca(), "CA cap");

__host__ __device__ constexpr bool combo_in_phase(int ci,int ph){
  int l1=CB.l1[ci], l2=CB.l2[ci], L=CB.L[ci];
  if(ph==0) return l1<=2;
  if(ph==1) return l1==3;
  int kt=ph-1;
  return (l2<=3-kt) && (L<=3-kt);
}
__host__ __device__ constexpr int phase_kt(int ph){ return ph<=1?0:ph-1; }
__host__ __device__ constexpr int phase_rbadj(int ph){ return ph==1?144:0; }

// ---------------- host: numpy-legacy RandomState(0) CG generation ----------------
namespace nprng {
struct MT {
  uint32_t mt[624]; int mti; bool has_g; double g;
  void seed(uint32_t s){ for(int i=0;i<624;i++){ mt[i]=s; s=1812433253u*(s^(s>>30))+(uint32_t)i+1u; } mti=624; has_g=false; g=0.0; }
  uint32_t u32(){
    if(mti>=624){
      for(int i=0;i<624;i++){
        uint32_t y=(mt[i]&0x80000000u)|(mt[(i+1)%624]&0x7fffffffu);
        mt[i]=mt[(i+397)%624]^(y>>1)^((y&1u)?0x9908b0dfu:0u);
      }
      mti=0;
    }
    uint32_t y=mt[mti++];
    y^=y>>11; y^=(y<<7)&0x9d2c5680u; y^=(y<<15)&0xefc60000u; y^=y>>18;
    return y;
  }
  double dbl(){ uint32_t a=u32()>>5, b=u32()>>6; return (a*67108864.0+b)/9007199254740992.0; }
  double gauss(){
    if(has_g){ has_g=false; return g; }
    double f,x1,x2,r2;
    do{ x1=2.0*dbl()-1.0; x2=2.0*dbl()-1.0; r2=x1*x1+x2*x2; }while(r2>=1.0||r2==0.0);
    f=sqrt(-2.0*log(r2)/r2);
    g=f*x1; has_g=true; return f*x2;
  }
};
}
static std::vector<float> build_cg(){
  nprng::MT r; r.seed(0);
  std::vector<float> v; v.reserve(CGTOT);
  for(int l1=0;l1<=3;l1++)for(int l2=0;l2<=3;l2++){
    int lo = l1>l2? l1-l2 : l2-l1;
    int hi = (l1+l2<3)? (l1+l2) : 3;
    for(int L=lo;L<=hi;L++){
      int n=(2*l1+1)*(2*l2+1)*(2*L+1);
      for(int i=0;i<n;i++) v.push_back((float)(r.gauss()*0.2));
    }
  }
  return v;
}

// ---------------- small setup kernels ----------------
__global__ __launch_bounds__(256) void k_cemb(const float* __restrict__ emb_table,
    const int* __restrict__ species, float* __restrict__ cemb, int* __restrict__ counts, int N){
  int i = blockIdx.x*256 + threadIdx.x;
  if(i < N) counts[i] = 0;
  if(i < N*32){ int n = i>>5, c = i&31; cemb[i] = emb_table[species[n]*32 + c]; }
}

__global__ __launch_bounds__(256) void k_hist(const int* __restrict__ centers, int* counts, int P){
  int i = blockIdx.x*256 + threadIdx.x;
  if(i < P) atomicAdd(&counts[centers[i]], 1);
}

__global__ __launch_bounds__(256) void k_scan(const int* __restrict__ counts,
    int* __restrict__ offsets, int* __restrict__ cursor, int N){
  __shared__ int part[256];
  const int t = threadIdx.x;
  const int CH = (N + 255)/256;
  const int lo = t*CH;
  int hi = (t+1)*CH; if(hi > N) hi = N;
  int s = 0;
  for(int i=lo;i<hi;i++) s += counts[i];
  part[t] = s; __syncthreads();
  const int own = s;
  for(int d=1; d<256; d<<=1){
    int v = (t>=d)? part[t-d] : 0;
    __syncthreads();
    part[t] += v;
    __syncthreads();
  }
  int run = part[t] - own;
  for(int i=lo;i<hi;i++){ offsets[i]=run; cursor[i]=run; run += counts[i]; }
  if(t==255) offsets[N] = part[255];
}

__global__ __launch_bounds__(256) void k_scatter(const int* __restrict__ centers,
    int* cursor, int* __restrict__ perm, int P){
  int i = blockIdx.x*256 + threadIdx.x;
  if(i < P){ int c = centers[i]; int pos = atomicAdd(&cursor[c], 1); perm[pos] = i; }
}

// ---------------- invariant MP (batched pairs, 3 barriers / 8 pairs) ----------------
__global__ __launch_bounds__(256) void k_inv(const float* __restrict__ sh, const float* __restrict__ rb,
    const float* __restrict__ cemb, const int* __restrict__ nbrs, const int* __restrict__ offsets,
    const int* __restrict__ perm, float* __restrict__ feats){
  const int a = blockIdx.x, t = threadIdx.x;
  __shared__ float sh_s[8][16], rb_s[8][20], emb_s[8][32], shrb_s[8][60];
  const int c = t & 31, rg = t >> 5;
  float acc[8];
  #pragma unroll
  for(int j=0;j<8;j++) acc[j] = 0.f;
  const int beg = offsets[a], cnt = offsets[a+1]-beg;
  for(int jb=0; jb<cnt; jb+=8){
    __syncthreads();
    for(int u=t; u<8*36; u+=256){
      int j=u/36, i=u-36*j;
      if(jb+j<cnt){
        int p=perm[beg+jb+j];
        if(i<16) sh_s[j][i]=sh[p*16+i]*0.1f;      // NU_SCALING
        else     rb_s[j][i-16]=rb[p*20+i-16];
      }
    }
    for(int u=t; u<8*32; u+=256){
      int j=u>>5, i=u&31;
      if(jb+j<cnt){ int nb=nbrs[perm[beg+jb+j]]; emb_s[j][i]=cemb[(size_t)nb*32+i]; }
    }
    __syncthreads();
    for(int u=t; u<8*60; u+=256){
      int j=u/60, r=u-60*j;
      if(jb+j<cnt) shrb_s[j][r] = sh_s[j][RWS.sh[r]] * rb_s[j][RWS.rb[r]];
    }
    __syncthreads();
    const int jm = (cnt-jb<8)?(cnt-jb):8;
    for(int j=0;j<jm;j++){
      const float e = emb_s[j][c];
      #pragma unroll
      for(int q=0;q<8;q++){ int r=rg+8*q; if(r<60) acc[q]=fmaf(shrb_s[j][r], e, acc[q]); }
    }
  }
  #pragma unroll
  for(int q=0;q<8;q++){
    int r = rg + 8*q;
    if(r < 60) feats[(size_t)a*FTOT + RWS.off[r] + c] = 0.1f * acc[q];  // MP_SCALING
  }
}

// ---------------- CG iterate (in-place): feats = (feats + 0.1*TP(feats,feats)) * cemb ----------------
// embed_centers fused into epilogue (both consumers want it applied).
__global__ __launch_bounds__(256) void k_tp(float* __restrict__ feats, const float* __restrict__ cg,
    const float* __restrict__ cemb){
  const int a = blockIdx.x, t = threadIdx.x;
  __shared__ float f_s[FTOT];
  __shared__ float cemb_s[32];
  float* fa = feats + (size_t)a*FTOT;
  if(t < 32) cemb_s[t] = cemb[(size_t)a*32 + t];
  for(int i=t;i<FTOT;i+=256)  f_s[i]  = fa[i];
  __syncthreads();
  #pragma unroll
  for(int L=0; L<4; L++){
    const int KLL = KLc[L], nL = 2*L+1;
    const int nel = nL*KLL;
    for(int e=t; e<nel; e+=256){
      const int M = e / KLL, k = e - M*KLL;
      float acc = 0.f;
      #pragma unroll
      for(int gi=0; gi<LG.cnt[L]; gi++){
        const int ci = LG.list[L][gi];
        const int l1 = CB.l1[ci], l2 = CB.l2[ci];
        if(k < CB.kk[ci]){
          const int n2 = 2*l2+1;
          #pragma unroll
          for(int aa=0; aa<2*l1+1; aa++){
            const float Av = f_s[FBc[l1] + aa*KLc[l1] + k];
            #pragma unroll
            for(int b=0; b<n2; b++)
              acc += cg[CB.cgoff[ci] + (aa*n2+b)*nL + M] * (Av * f_s[FBc[l2] + b*KLc[l2] + k]);
          }
        }
      }
      fa[FBc[L] + M*KLL + k] = (f_s[FBc[L] + M*KLL + k] + 0.1f*acc) * cemb_s[k & 31];
    }
  }
}

// ---------------- equivariant MP v5: ping-pong 4-pair register buffers (macros, no ptr-passing) ----------------
template<int G,int PH,int U>
__device__ __forceinline__ void contract_combos(const float* __restrict__ stageT,
    float* __restrict__ out_s, const float* __restrict__ cg, int lane){
  if constexpr (U < CA.cnt[G]) {
    constexpr int ci = CA.ci[G][U];
    if constexpr (combo_in_phase(ci,PH)) {
      constexpr int l1=CB.l1[ci], l2=CB.l2[ci], L=CB.L[ci];
      constexpr int n1=2*l1+1, n2=2*l2+1, nL=2*L+1;
      constexpr int kt=phase_kt(PH);
      constexpr int rbase = rb_base(kt,l1,l2) - phase_rbadj(PH);
      float oa[nL];
      #pragma unroll
      for(int M=0;M<nL;M++) oa[M]=0.f;
      #pragma unroll
      for(int aa=0;aa<n1;aa++){
        #pragma unroll
        for(int b=0;b<n2;b++){
          const float sv = stageT[lane*RPAD + rbase + aa*n2 + b];
          #pragma unroll
          for(int M=0;M<nL;M++)
            oa[M] = fmaf(cg[CB.cgoff[ci] + (aa*n2+b)*nL + M], sv, oa[M]);  // uniform idx -> s_load
        }
      }
      #pragma unroll
      for(int M=0;M<nL;M++)
        atomicAdd(&out_s[FBc[L] + M*KLc[L] + kt*64 + lane], oa[M]);
    }
    contract_combos<G,PH,U+1>(stageT,out_s,cg,lane);
  }
}

template<int G,int PH>
__device__ __forceinline__ void eq_phase(const float* acc, float* stageT, float* out_s,
    const float* __restrict__ cg, int lane){
  __syncthreads();                       // protect previous phase's stage reads
  #pragma unroll
  for(int s=0;s<ET.ns[G];s++){
    if(ET.sph[G][s]==PH) stageT[lane*RPAD + ET.srow[G][s]] = acc[s];
  }
  __syncthreads();
  contract_combos<G,PH,0>(stageT,out_s,cg,lane);
}

// macros operate on named locals in eq_group_main scope (NO pointer passing -> SROA-safe)
#define EQ_LOADSUB(BUF, J0) do{                                                 \
    _Pragma("unroll")                                                           \
    for(int p_=0;p_<4;p_++){                                                    \
      int jn_ = (J0)+p_; if(jn_ > cnt-1) jn_ = cnt-1;                           \
      const int nb_ = (jn_ < 128) ? nb_s[jn_] : nbrs[perm[beg+jn_]];            \
      const float* fp_ = featsA + (size_t)nb_*FTOT + lane;                      \
      _Pragma("unroll")                                                         \
      for(int r_=0;r_<NR;r_++) BUF[p_][r_] = fp_[ET.roff[G][r_]];               \
    } }while(0)

#define EQ_COMPSUB(BUF, J0) do{                                                 \
    _Pragma("unroll")                                                           \
    for(int p_=0;p_<4;p_++){                                                    \
      const int jj_ = ((J0)+p_) - jb;                                           \
      float ed_[16];                                                            \
      _Pragma("unroll")                                                         \
      for(int q_=0;q_<4;q_++){                                                  \
        float4 v_ = *(const float4*)(edge_s + jj_*16 + q_*4);                   \
        ed_[q_*4]=v_.x; ed_[q_*4+1]=v_.y; ed_[q_*4+2]=v_.z; ed_[q_*4+3]=v_.w; } \
      _Pragma("unroll")                                                         \
      for(int q_=0;q_<NS;q_++)                                                  \
        acc[q_] = fmaf(ed_[ET.eidx[G][q_]], BUF[p_][ET.fidx[G][q_]], acc[q_]);  \
    } }while(0)

template<int G>
__device__ __forceinline__ void eq_group_main(
    const int a, const int t, const int lane,
    const float* __restrict__ sh, const float* __restrict__ rb,
    const int* __restrict__ nbrs, const int* __restrict__ offsets,
    const int* __restrict__ perm,
    const float* __restrict__ featsA, float* __restrict__ featsB,
    const float* __restrict__ cg,
    float* stageT, float* out_s, float* edge_s, int* nb_s){
  constexpr int NS = ET.ns[G], NR = ET.nr[G];
  float acc[NS];
  #pragma unroll
  for(int q=0;q<NS;q++) acc[q]=0.f;
  for(int i=t;i<FTOT;i+=512) out_s[i]=0.f;
  const int beg = offsets[a], cnt = offsets[a+1]-beg;
  const int nbcap = cnt<128?cnt:128;
  for(int i=t;i<nbcap;i+=512) nb_s[i] = nbrs[perm[beg+i]];
  __syncthreads();
  float bufA[4][NR], bufB[4][NR];
  if(cnt > 0) EQ_LOADSUB(bufA, 0);           // prime pairs 0..3
  for(int jb=0; jb<cnt; jb+=16){
    __syncthreads();                          // edge_s reuse guard
    if(t < 256){
      const int j=t>>4, i=t&15, jj=jb+j;
      float ev = 0.f;
      if(jj < cnt){
        const int p = perm[beg+jj];
        const int l = (i==0)?0:(i<4)?1:(i<9)?2:3;
        float ssum = 0.f;
        for(int n=RBBc[l]; n<RBBc[l+1]; n++) ssum += rb[p*20+n];
        ev = sh[p*16+i]*0.1f*ssum;            // sh * NU_SCALING * rb.sum
      }
      edge_s[j*16+i] = ev;
    }
    __syncthreads();
    EQ_LOADSUB(bufB, jb+4);  EQ_COMPSUB(bufA, jb);     // loads in flight during compute
    EQ_LOADSUB(bufA, jb+8);  EQ_COMPSUB(bufB, jb+4);
    EQ_LOADSUB(bufB, jb+12); EQ_COMPSUB(bufA, jb+8);
    EQ_LOADSUB(bufA, jb+16); EQ_COMPSUB(bufB, jb+12);  // last load primes next batch
  }
  eq_phase<G,0>(acc,stageT,out_s,cg,lane);
  eq_phase<G,1>(acc,stageT,out_s,cg,lane);
  eq_phase<G,2>(acc,stageT,out_s,cg,lane);
  eq_phase<G,3>(acc,stageT,out_s,cg,lane);
  eq_phase<G,4>(acc,stageT,out_s,cg,lane);
  __syncthreads();
  float* ob = featsB + (size_t)a*FTOT;
  for(int i=t;i<FTOT;i+=512) ob[i] = 0.1f*out_s[i];     // MP_SCALING
}
#undef EQ_LOADSUB
#undef EQ_COMPSUB

__global__ __launch_bounds__(512,4) void k_eq2(const float* __restrict__ sh, const float* __restrict__ rb,
    const int* __restrict__ nbrs, const int* __restrict__ offsets,
    const int* __restrict__ perm, const float* __restrict__ featsA, float* __restrict__ featsB,
    const float* __restrict__ cg){
  __shared__ float stageT[64*RPAD];   // 38144 B, odd lane stride -> conflict-free
  __shared__ float out_s[FTOT];       // 7680 B
  __shared__ float edge_s[16*16];
  __shared__ int   nb_s[128];
  const int a = blockIdx.x, t = threadIdx.x, lane = t&63, g = t>>6;
  switch(g){  // wave-uniform branch; identical barrier structure in every case
    case 0: eq_group_main<0>(a,t,lane,sh,rb,nbrs,offsets,perm,featsA,featsB,cg,stageT,out_s,edge_s,nb_s); break;
    case 1: eq_group_main<1>(a,t,lane,sh,rb,nbrs,offsets,perm,featsA,featsB,cg,stageT,out_s,edge_s,nb_s); break;
    case 2: eq_group_main<2>(a,t,lane,sh,rb,nbrs,offsets,perm,featsA,featsB,cg,stageT,out_s,edge_s,nb_s); break;
    case 3: eq_group_main<3>(a,t,lane,sh,rb,nbrs,offsets,perm,featsA,featsB,cg,stageT,out_s,edge_s,nb_s); break;
    case 4: eq_group_main<4>(a,t,lane,sh,rb,nbrs,offsets,perm,featsA,featsB,cg,stageT,out_s,edge_s,nb_s); break;
    case 5: eq_group_main<5>(a,t,lane,sh,rb,nbrs,offsets,perm,featsA,featsB,cg,stageT,out_s,edge_s,nb_s); break;
    case 6: eq_group_main<6>(a,t,lane,sh,rb,nbrs,offsets,perm,featsA,featsB,cg,stageT,out_s,edge_s,nb_s); break;
    default: eq_group_main<7>(a,t,lane,sh,rb,nbrs,offsets,perm,featsA,featsB,cg,stageT,out_s,edge_s,nb_s); break;
  }
}

// ---------------- energy readout (embed already folded into feats by k_tp) ----------------
__global__ __launch_bounds__(256) void k_energy(const float* __restrict__ feats,
    const float* __restrict__ wE, const float* __restrict__ bE,
    float* __restrict__ out, int N){
  const int wid = threadIdx.x >> 6, lane = threadIdx.x & 63;
  const int a = blockIdx.x*4 + wid;
  if(a >= N) return;
  float s = 0.f;
  for(int k=lane; k<256; k+=64) s += feats[(size_t)a*FTOT + k] * wE[k];
  #pragma unroll
  for(int off=32; off; off>>=1) s += __shfl_down(s, off, 64);
  if(lane == 0) out[a] = s + bE[0];
}

// ---------------- launcher ----------------
extern "C" void kernel_launch(void* const* d_in, const int* in_sizes, int n_in,
                              void* d_out, int out_size, void* d_ws, size_t ws_size,
                              hipStream_t stream){
  const float* sh        = (const float*)d_in[0];
  const float* rb        = (const float*)d_in[1];
  const float* emb_table = (const float*)d_in[2];
  const float* wE        = (const float*)d_in[3];
  const float* bE        = (const float*)d_in[4];
  const int*   species   = (const int*)d_in[5];
  const int*   centers   = (const int*)d_in[6];
  const int*   nbrs      = (const int*)d_in[7];
  const int N = in_sizes[5];
  const int P = in_sizes[6];

  char* ws = (char*)d_ws; size_t off = 0;
  auto carve = [&](size_t bytes)->void*{
    void* p = ws + off; off = (off + bytes + 255) & ~(size_t)255; return p;
  };
  float* cg_d    = (float*)carve((size_t)CGTOT*4);
  float* cemb    = (float*)carve((size_t)N*32*4);
  int*   counts  = (int*)  carve((size_t)N*4);
  int*   offsets = (int*)  carve((size_t)(N+1)*4);
  int*   cursor  = (int*)  carve((size_t)N*4);
  int*   perm    = (int*)  carve((size_t)P*4);
  float* featsA  = (float*)carve((size_t)N*FTOT*4);
  float* featsB  = (float*)carve((size_t)N*FTOT*4);
  (void)ws_size; (void)n_in; (void)out_size;

  static const std::vector<float> cg_host = build_cg();  // deterministic; host-side cache only
  hipMemcpyAsync(cg_d, cg_host.data(), (size_t)CGTOT*4, hipMemcpyHostToDevice, stream);

  k_cemb   <<<(N*32 + 255)/256, 256, 0, stream>>>(emb_table, species, cemb, counts, N);
  k_hist   <<<(P + 255)/256,    256, 0, stream>>>(centers, counts, P);
  k_scan   <<<1,                256, 0, stream>>>(counts, offsets, cursor, N);
  k_scatter<<<(P + 255)/256,    256, 0, stream>>>(centers, cursor, perm, P);
  k_inv    <<<N,                256, 0, stream>>>(sh, rb, cemb, nbrs, offsets, perm, featsA);
  k_tp     <<<N,                256, 0, stream>>>(featsA, cg_d, cemb);
  k_eq2    <<<N,                512, 0, stream>>>(sh, rb, nbrs, offsets, perm, featsA, featsB, cg_d);
  k_tp     <<<N,                256, 0, stream>>>(featsB, cg_d, cemb);
  k_energy <<<(N + 3)/4,        256, 0, stream>>>(featsB, wE, bE, (float*)d_out, N);
}

// Round 6
// 1039.199 us; speedup vs baseline: 2.8661x; 2.8661x over previous
//
#include <hip/hip_runtime.h>
#include <vector>
#include <cmath>
#include <cstdint>

// ---------------- static model tables (constexpr, device-usable) ----------------
constexpr int KLc[4]  = {256,192,128,64};     // k_max per l
constexpr int NMLc[4] = {8,6,4,2};            // radial basis per l
constexpr int SHBc[5] = {0,1,4,9,16};         // sh split bases
constexpr int RBBc[5] = {0,8,14,18,20};       // rb split bases
constexpr int FBc[5]  = {0,256,832,1472,1920};// feats flat base per l  (sum (2l+1)*K[l])
constexpr int NCMB = 34, CGTOT = 3436, FTOT = 1920;

struct Combos { int l1[NCMB], l2[NCMB], L[NCMB], cgoff[NCMB], kk[NCMB]; };
constexpr Combos make_combos(){
  Combos c{}; int n=0, cg=0;
  for(int a=0;a<=3;a++)for(int b=0;b<=3;b++){
    int lo=a>b?a-b:b-a, hi=(a+b<3)?(a+b):3;
    for(int L=lo;L<=hi;L++){
      c.l1[n]=a; c.l2[n]=b; c.L[n]=L; c.cgoff[n]=cg;
      int mx=a>b?a:b; if(L>mx) mx=L; c.kk[n]=KLc[mx];          // TP truncation (min of all three)
      cg+=(2*a+1)*(2*b+1)*(2*L+1); n++;
    }
  }
  return c;
}
constexpr Combos CB = make_combos();
static_assert(CB.cgoff[NCMB-1] + 7*7*7 == CGTOT, "cg size");

struct Grp { int cnt[4]; int list[4][12]; };
constexpr Grp make_Lg(){ Grp g{}; for(int i=0;i<NCMB;i++){ int L=CB.L[i]; g.list[L][g.cnt[L]++]=i; } return g; }
constexpr Grp LG = make_Lg();     // combos grouped by output L (for k_tp)

struct Rows { int sh[64], rb[64], off[64]; };
constexpr Rows make_rows(){ Rows r{}; int i=0;
  for(int l=0;l<4;l++)for(int m=0;m<2*l+1;m++)for(int n=0;n<NMLc[l];n++){
    r.sh[i]=SHBc[l]+m; r.rb[i]=RBBc[l]+n; r.off[i]=FBc[l]+m*KLc[l]+n*32; i++; }
  for(;i<64;i++){ r.sh[i]=0; r.rb[i]=0; r.off[i]=0; }
  return r; }
constexpr Rows RWS = make_rows();  // 60 (l,m,n) rows for invariant MP

// ---------------- k_eq tables: S-factorization slices, row-partitioned 8 wave-groups ----------------
// S[l1,a,l2,b][k] = sum_pairs edge[l1,a] * femb[l2,b,k]; slice unit = (l1,a,l2,b,ktile)
// Slice valid iff l2 <= 3-kt && |l1-l2| <= 3-kt   (equivariant kk = min(K[l2],K[L]), L>=|l1-l2|)
// Rows (l2,b,kt) are partitioned across groups (greedy) so each feature row is gathered ONCE.
constexpr int NSL=425, NG=8, MAXS=57, MAXR=4, RPAD=149; // RPAD odd -> 2-way bank aliasing (free)
constexpr int CHUNK=128;           // pairs staged (edges+nb) per block barrier
constexpr int GSLOT=256;           // floats per gather slot: 4 rows x 64
constexpr int GREG=8*GSLOT;        // 8-slot ring per wave-group

constexpr int iabs_(int x){ return x<0?-x:x; }
__host__ __device__ constexpr bool sl_valid(int l1,int l2,int kt){ return l2<=3-kt && iabs_(l1-l2)<=3-kt; }

__host__ __device__ constexpr int rb_base(int kt,int l1,int l2){
  int base=0;
  for(int p=0;p<4;p++)for(int q=0;q<4;q++){
    if(p==l1 && q==l2) return base;
    if(sl_valid(p,q,kt)) base += (2*p+1)*(2*q+1);
  }
  return base;
}

struct EqTab {
  int ns[NG];
  unsigned char eidx[NG][MAXS];   // edge register index (SHB[l1]+a)
  unsigned char fidx[NG][MAXS];   // row index within group (0..NR-1)
  short         srow[NG][MAXS];   // stage row within its dump phase
  unsigned char sph [NG][MAXS];   // dump phase 0..4
  int nr[NG];
  short roff[NG][MAXR];           // feature row offsets into feats (element units)
  int total;
};
constexpr EqTab make_eqtab(){
  EqTab T{};
  int rl2[30], rbb[30], rkt[30], rsc[30]; int nrw=0;
  for(int l2=0;l2<4;l2++)for(int kt=0;kt<4-l2;kt++)for(int b=0;b<2*l2+1;b++){
    int sc=0; for(int l1=0;l1<4;l1++) if(sl_valid(l1,l2,kt)) sc+=2*l1+1;
    rl2[nrw]=l2; rbb[nrw]=b; rkt[nrw]=kt; rsc[nrw]=sc; nrw++;
  }
  bool used[30]={}; int load[NG]={};
  for(int it=0; it<nrw; it++){
    int best=-1,bsc=-1;
    for(int i=0;i<nrw;i++) if(!used[i] && rsc[i]>bsc){bsc=rsc[i];best=i;}
    used[best]=true;
    int g=0; for(int j=1;j<NG;j++) if(load[j]<load[g]) g=j;
    load[g]+=bsc;
    const int l2=rl2[best], b=rbb[best], kt=rkt[best];
    const int ri = T.nr[g];
    T.roff[g][T.nr[g]++] = (short)(FBc[l2]+b*KLc[l2]+kt*64);
    for(int l1=0;l1<4;l1++){
      if(!sl_valid(l1,l2,kt)) continue;
      for(int a=0;a<2*l1+1;a++){
        int s=T.ns[g]++;
        T.eidx[g][s]=(unsigned char)(SHBc[l1]+a);
        T.fidx[g][s]=(unsigned char)ri;
        int rbi = rb_base(kt,l1,l2)+a*(2*l2+1)+b;
        int ph,sr;
        if(kt==0){ if(l1<=2){ph=0;sr=rbi;} else {ph=1;sr=rbi-144;} }
        else {ph=kt+1;sr=rbi;}
        T.sph[g][s]=(unsigned char)ph; T.srow[g][s]=(short)sr;
        T.total++;
      }
    }
  }
  return T;
}
constexpr EqTab ET = make_eqtab();
static_assert(ET.total==NSL, "slice count");
constexpr bool chk_ns(){ for(int g=0;g<NG;g++) if(ET.ns[g]>MAXS) return false; return true; }
constexpr bool chk_nr(){ for(int g=0;g<NG;g++) if(ET.nr[g]>MAXR) return false; return true; }
static_assert(chk_ns(), "MAXS");
static_assert(chk_nr(), "MAXR");

// contraction combo -> group assignment (greedy by cost n1*n2*nL)
struct CAsg { int cnt[NG]; unsigned char ci[NG][8]; };
constexpr CAsg make_casg(){
  CAsg C{}; bool used[NCMB]{}; int load[NG]{};
  for(int it=0; it<NCMB; it++){
    int best=-1, bc=-1;
    for(int i=0;i<NCMB;i++) if(!used[i]){
      int c=(2*CB.l1[i]+1)*(2*CB.l2[i]+1)*(2*CB.L[i]+1);
      if(c>bc){bc=c;best=i;}
    }
    used[best]=true;
    int g=0; for(int j=1;j<NG;j++) if(load[j]<load[g]) g=j;
    C.ci[g][C.cnt[g]++]=(unsigned char)best; load[g]+=bc;
  }
  return C;
}
constexpr CAsg CA = make_casg();
constexpr bool chk_ca(){ for(int g=0;g<NG;g++) if(CA.cnt[g]>8) return false; return true; }
static_assert(chk_ca(), "CA cap");

__host__ __device__ constexpr bool combo_in_phase(int ci,int ph){
  int l1=CB.l1[ci], l2=CB.l2[ci], L=CB.L[ci];
  if(ph==0) return l1<=2;
  if(ph==1) return l1==3;
  int kt=ph-1;
  return (l2<=3-kt) && (L<=3-kt);
}
__host__ __device__ constexpr int phase_kt(int ph){ return ph<=1?0:ph-1; }
__host__ __device__ constexpr int phase_rbadj(int ph){ return ph==1?144:0; }

// waitcnt immediates (gfx9 encoding): vmcnt lo[3:0] hi[15:14], expcnt[6:4]=7, lgkmcnt[11:8]=15
constexpr int vmimm(int n){ return (n&15) | ((n>>4)<<14) | (7<<4) | (15<<8); }

// async global->LDS: per-lane 16B, LDS dest = uniform base + lane*16
__device__ __forceinline__ void gload_lds16(const float* g, float* l){
  __builtin_amdgcn_global_load_lds((const __attribute__((address_space(1))) void*)g,
                                   (__attribute__((address_space(3))) void*)l, 16, 0, 0);
}

// ---------------- host: numpy-legacy RandomState(0) CG generation ----------------
namespace nprng {
struct MT {
  uint32_t mt[624]; int mti; bool has_g; double g;
  void seed(uint32_t s){ for(int i=0;i<624;i++){ mt[i]=s; s=1812433253u*(s^(s>>30))+(uint32_t)i+1u; } mti=624; has_g=false; g=0.0; }
  uint32_t u32(){
    if(mti>=624){
      for(int i=0;i<624;i++){
        uint32_t y=(mt[i]&0x80000000u)|(mt[(i+1)%624]&0x7fffffffu);
        mt[i]=mt[(i+397)%624]^(y>>1)^((y&1u)?0x9908b0dfu:0u);
      }
      mti=0;
    }
    uint32_t y=mt[mti++];
    y^=y>>11; y^=(y<<7)&0x9d2c5680u; y^=(y<<15)&0xefc60000u; y^=y>>18;
    return y;
  }
  double dbl(){ uint32_t a=u32()>>5, b=u32()>>6; return (a*67108864.0+b)/9007199254740992.0; }
  double gauss(){
    if(has_g){ has_g=false; return g; }
    double f,x1,x2,r2;
    do{ x1=2.0*dbl()-1.0; x2=2.0*dbl()-1.0; r2=x1*x1+x2*x2; }while(r2>=1.0||r2==0.0);
    f=sqrt(-2.0*log(r2)/r2);
    g=f*x1; has_g=true; return f*x2;
  }
};
}
static std::vector<float> build_cg(){
  nprng::MT r; r.seed(0);
  std::vector<float> v; v.reserve(CGTOT);
  for(int l1=0;l1<=3;l1++)for(int l2=0;l2<=3;l2++){
    int lo = l1>l2? l1-l2 : l2-l1;
    int hi = (l1+l2<3)? (l1+l2) : 3;
    for(int L=lo;L<=hi;L++){
      int n=(2*l1+1)*(2*l2+1)*(2*L+1);
      for(int i=0;i<n;i++) v.push_back((float)(r.gauss()*0.2));
    }
  }
  return v;
}

// ---------------- small setup kernels ----------------
__global__ __launch_bounds__(256) void k_cemb(const float* __restrict__ emb_table,
    const int* __restrict__ species, float* __restrict__ cemb, int* __restrict__ counts, int N){
  int i = blockIdx.x*256 + threadIdx.x;
  if(i < N) counts[i] = 0;
  if(i < N*32){ int n = i>>5, c = i&31; cemb[i] = emb_table[species[n]*32 + c]; }
}

__global__ __launch_bounds__(256) void k_hist(const int* __restrict__ centers, int* counts, int P){
  int i = blockIdx.x*256 + threadIdx.x;
  if(i < P) atomicAdd(&counts[centers[i]], 1);
}

__global__ __launch_bounds__(256) void k_scan(const int* __restrict__ counts,
    int* __restrict__ offsets, int* __restrict__ cursor, int N){
  __shared__ int part[256];
  const int t = threadIdx.x;
  const int CH = (N + 255)/256;
  const int lo = t*CH;
  int hi = (t+1)*CH; if(hi > N) hi = N;
  int s = 0;
  for(int i=lo;i<hi;i++) s += counts[i];
  part[t] = s; __syncthreads();
  const int own = s;
  for(int d=1; d<256; d<<=1){
    int v = (t>=d)? part[t-d] : 0;
    __syncthreads();
    part[t] += v;
    __syncthreads();
  }
  int run = part[t] - own;
  for(int i=lo;i<hi;i++){ offsets[i]=run; cursor[i]=run; run += counts[i]; }
  if(t==255) offsets[N] = part[255];
}

__global__ __launch_bounds__(256) void k_scatter(const int* __restrict__ centers,
    int* cursor, int* __restrict__ perm, int P){
  int i = blockIdx.x*256 + threadIdx.x;
  if(i < P){ int c = centers[i]; int pos = atomicAdd(&cursor[c], 1); perm[pos] = i; }
}

// ---------------- invariant MP (batched pairs, 3 barriers / 8 pairs) ----------------
__global__ __launch_bounds__(256) void k_inv(const float* __restrict__ sh, const float* __restrict__ rb,
    const float* __restrict__ cemb, const int* __restrict__ nbrs, const int* __restrict__ offsets,
    const int* __restrict__ perm, float* __restrict__ feats){
  const int a = blockIdx.x, t = threadIdx.x;
  __shared__ float sh_s[8][16], rb_s[8][20], emb_s[8][32], shrb_s[8][60];
  const int c = t & 31, rg = t >> 5;
  float acc[8];
  #pragma unroll
  for(int j=0;j<8;j++) acc[j] = 0.f;
  const int beg = offsets[a], cnt = offsets[a+1]-beg;
  for(int jb=0; jb<cnt; jb+=8){
    __syncthreads();
    for(int u=t; u<8*36; u+=256){
      int j=u/36, i=u-36*j;
      if(jb+j<cnt){
        int p=perm[beg+jb+j];
        if(i<16) sh_s[j][i]=sh[p*16+i]*0.1f;      // NU_SCALING
        else     rb_s[j][i-16]=rb[p*20+i-16];
      }
    }
    for(int u=t; u<8*32; u+=256){
      int j=u>>5, i=u&31;
      if(jb+j<cnt){ int nb=nbrs[perm[beg+jb+j]]; emb_s[j][i]=cemb[(size_t)nb*32+i]; }
    }
    __syncthreads();
    for(int u=t; u<8*60; u+=256){
      int j=u/60, r=u-60*j;
      if(jb+j<cnt) shrb_s[j][r] = sh_s[j][RWS.sh[r]] * rb_s[j][RWS.rb[r]];
    }
    __syncthreads();
    const int jm = (cnt-jb<8)?(cnt-jb):8;
    for(int j=0;j<jm;j++){
      const float e = emb_s[j][c];
      #pragma unroll
      for(int q=0;q<8;q++){ int r=rg+8*q; if(r<60) acc[q]=fmaf(shrb_s[j][r], e, acc[q]); }
    }
  }
  #pragma unroll
  for(int q=0;q<8;q++){
    int r = rg + 8*q;
    if(r < 60) feats[(size_t)a*FTOT + RWS.off[r] + c] = 0.1f * acc[q];  // MP_SCALING
  }
}

// ---------------- CG iterate (in-place): feats = (feats + 0.1*TP(feats,feats)) * cemb ----------------
// embed_centers fused into epilogue (both consumers want it applied).
__global__ __launch_bounds__(256) void k_tp(float* __restrict__ feats, const float* __restrict__ cg,
    const float* __restrict__ cemb){
  const int a = blockIdx.x, t = threadIdx.x;
  __shared__ float f_s[FTOT];
  __shared__ float cemb_s[32];
  float* fa = feats + (size_t)a*FTOT;
  if(t < 32) cemb_s[t] = cemb[(size_t)a*32 + t];
  for(int i=t;i<FTOT;i+=256)  f_s[i]  = fa[i];
  __syncthreads();
  #pragma unroll
  for(int L=0; L<4; L++){
    const int KLL = KLc[L], nL = 2*L+1;
    const int nel = nL*KLL;
    for(int e=t; e<nel; e+=256){
      const int M = e / KLL, k = e - M*KLL;
      float acc = 0.f;
      #pragma unroll
      for(int gi=0; gi<LG.cnt[L]; gi++){
        const int ci = LG.list[L][gi];
        const int l1 = CB.l1[ci], l2 = CB.l2[ci];
        if(k < CB.kk[ci]){
          const int n2 = 2*l2+1;
          #pragma unroll
          for(int aa=0; aa<2*l1+1; aa++){
            const float Av = f_s[FBc[l1] + aa*KLc[l1] + k];
            #pragma unroll
            for(int b=0; b<n2; b++)
              acc += cg[CB.cgoff[ci] + (aa*n2+b)*nL + M] * (Av * f_s[FBc[l2] + b*KLc[l2] + k]);
          }
        }
      }
      fa[FBc[L] + M*KLL + k] = (f_s[FBc[L] + M*KLL + k] + 0.1f*acc) * cemb_s[k & 31];
    }
  }
}

// ---------------- equivariant MP v6: async global->LDS gather ring, per-wave pipeline ----------------
template<int G,int PH,int U>
__device__ __forceinline__ void contract_combos(const float* __restrict__ stageT,
    float* __restrict__ out_s, const float* __restrict__ cg, int lane){
  if constexpr (U < CA.cnt[G]) {
    constexpr int ci = CA.ci[G][U];
    if constexpr (combo_in_phase(ci,PH)) {
      constexpr int l1=CB.l1[ci], l2=CB.l2[ci], L=CB.L[ci];
      constexpr int n1=2*l1+1, n2=2*l2+1, nL=2*L+1;
      constexpr int kt=phase_kt(PH);
      constexpr int rbase = rb_base(kt,l1,l2) - phase_rbadj(PH);
      float oa[nL];
      #pragma unroll
      for(int M=0;M<nL;M++) oa[M]=0.f;
      #pragma unroll
      for(int aa=0;aa<n1;aa++){
        #pragma unroll
        for(int b=0;b<n2;b++){
          const float sv = stageT[lane*RPAD + rbase + aa*n2 + b];
          #pragma unroll
          for(int M=0;M<nL;M++)
            oa[M] = fmaf(cg[CB.cgoff[ci] + (aa*n2+b)*nL + M], sv, oa[M]);  // uniform idx -> s_load
        }
      }
      #pragma unroll
      for(int M=0;M<nL;M++)
        atomicAdd(&out_s[FBc[L] + M*KLc[L] + kt*64 + lane], oa[M]);
    }
    contract_combos<G,PH,U+1>(stageT,out_s,cg,lane);
  }
}

template<int G,int PH>
__device__ __forceinline__ void eq_phase(const float* acc, float* stageT, float* out_s,
    const float* __restrict__ cg, int lane){
  __syncthreads();                       // protect previous phase's stage reads
  #pragma unroll
  for(int s=0;s<ET.ns[G];s++){
    if(ET.sph[G][s]==PH) stageT[lane*RPAD + ET.srow[G][s]] = acc[s];
  }
  __syncthreads();
  contract_combos<G,PH,0>(stageT,out_s,cg,lane);
}

// issue one batch of 4 pairs into the wave-private LDS ring (one dwordx4 load each)
#define EQ_ISSUE4(JR0) do{                                                      \
    _Pragma("unroll")                                                           \
    for(int p_=0;p_<4;p_++){                                                    \
      int src_=(JR0)+p_; if(src_>rmax) src_=rmax;                               \
      const int dst_=((JR0)+p_)&7;                                              \
      const float* gp_ = featsA + (size_t)nb_s[src_]*FTOT + roffl + ((lane&15)<<2); \
      gload_lds16(gp_, gbuf + dst_*GSLOT);                                      \
    } }while(0)

// compute one batch of 4 pairs from LDS ring slots (edge=0 padding kills clamped pairs)
#define EQ_COMP4(JR0) do{                                                       \
    _Pragma("unroll")                                                           \
    for(int p_=0;p_<4;p_++){                                                    \
      const int rel_=(JR0)+p_, slot_=rel_&7;                                    \
      float ed_[16];                                                            \
      _Pragma("unroll")                                                         \
      for(int q_=0;q_<4;q_++){                                                  \
        float4 v_ = *(const float4*)(edge_s + rel_*16 + q_*4);                  \
        ed_[q_*4]=v_.x; ed_[q_*4+1]=v_.y; ed_[q_*4+2]=v_.z; ed_[q_*4+3]=v_.w; } \
      float fv_[4];                                                             \
      _Pragma("unroll")                                                         \
      for(int r_=0;r_<NR;r_++) fv_[r_] = gbuf[slot_*GSLOT + r_*64 + lane];      \
      _Pragma("unroll")                                                         \
      for(int q_=0;q_<NS;q_++)                                                  \
        acc[q_] = fmaf(ed_[ET.eidx[G][q_]], fv_[ET.fidx[G][q_]], acc[q_]);      \
    } }while(0)

template<int G>
__device__ __forceinline__ void eq_group_main(
    const int a, const int t, const int lane,
    const float* __restrict__ sh, const float* __restrict__ rb,
    const int* __restrict__ nbrs, const int* __restrict__ offsets,
    const int* __restrict__ perm,
    const float* __restrict__ featsA, float* __restrict__ featsB,
    const float* __restrict__ cg,
    float* __restrict__ region, float* __restrict__ edge_s, int* __restrict__ nb_s){
  constexpr int NS = ET.ns[G], NR = ET.nr[G];
  float* gbuf = region + G*GREG;        // wave-private 8-slot gather ring
  float acc[NS];
  #pragma unroll
  for(int q=0;q<NS;q++) acc[q]=0.f;
  // per-lane row offset for the 16B staging load: lanes 16r..16r+15 carry row r
  const int rsel = lane>>4;
  int roffl = ET.roff[G][0];
  if constexpr (NR>1) { if(rsel==1) roffl = ET.roff[G][1]; }
  if constexpr (NR>2) { if(rsel==2) roffl = ET.roff[G][2]; }
  if constexpr (NR>3) { if(rsel==3) roffl = ET.roff[G][3]; }
  if(rsel>=NR) roffl = ET.roff[G][NR-1];   // duplicate last row into unused slot area
  const int beg=offsets[a], cnt=offsets[a+1]-beg;
  for(int c0=0; c0<cnt; c0+=CHUNK){
    const int clen = (cnt-c0<CHUNK)?(cnt-c0):CHUNK;
    const int rmax = clen-1;
    __syncthreads();                     // edge_s/nb_s reuse guard (also drains ring leftovers)
    for(int u=t; u<(CHUNK+4)*16; u+=512){
      const int j=u>>4, i=u&15, jj=c0+j;
      float ev=0.f;
      if(j<CHUNK && jj<cnt){
        const int p=perm[beg+jj];
        const int l=(i==0)?0:(i<4)?1:(i<9)?2:3;
        float ssum=0.f;
        for(int n=RBBc[l]; n<RBBc[l+1]; n++) ssum+=rb[p*20+n];
        ev=sh[p*16+i]*0.1f*ssum;         // sh * NU_SCALING * rb.sum
      }
      edge_s[u]=ev;
    }
    for(int u=t; u<CHUNK; u+=512){
      int jj=u; if(jj>rmax) jj=rmax;
      nb_s[u]=nbrs[perm[beg+c0+jj]];
    }
    __syncthreads();
    EQ_ISSUE4(0);                        // prime pairs 0..3 of chunk
    for(int jr=0; jr<clen; jr+=4){
      EQ_ISSUE4(jr+4);                   // next batch in flight during compute
      __builtin_amdgcn_s_waitcnt(vmimm(4));
      EQ_COMP4(jr);
    }
  }
  __builtin_amdgcn_s_waitcnt(vmimm(0)); // drain stray prefetches before LDS region reuse
  __syncthreads();
  float* out_s = region + 64*RPAD;      // epilogue union: stageT[0..9536) + out_s[9536..11456)
  for(int i=t;i<FTOT;i+=512) out_s[i]=0.f;
  eq_phase<G,0>(acc,region,out_s,cg,lane);
  eq_phase<G,1>(acc,region,out_s,cg,lane);
  eq_phase<G,2>(acc,region,out_s,cg,lane);
  eq_phase<G,3>(acc,region,out_s,cg,lane);
  eq_phase<G,4>(acc,region,out_s,cg,lane);
  __syncthreads();
  float* ob = featsB + (size_t)a*FTOT;
  for(int i=t;i<FTOT;i+=512) ob[i] = 0.1f*out_s[i];     // MP_SCALING
}
#undef EQ_ISSUE4
#undef EQ_COMP4

__global__ __launch_bounds__(512,4) void k_eq2(const float* __restrict__ sh, const float* __restrict__ rb,
    const int* __restrict__ nbrs, const int* __restrict__ offsets,
    const int* __restrict__ perm, const float* __restrict__ featsA, float* __restrict__ featsB,
    const float* __restrict__ cg){
  __shared__ float region[NG*GREG];        // 65536 B: gather rings (main) / stageT+out_s (epilogue)
  __shared__ float edge_s[(CHUNK+4)*16];   // 8448 B (tail-padded with zeros)
  __shared__ int   nb_s[CHUNK];            // 512 B
  const int a = blockIdx.x, t = threadIdx.x, lane = t&63, g = t>>6;
  switch(g){  // wave-uniform branch; identical barrier structure in every case
    case 0: eq_group_main<0>(a,t,lane,sh,rb,nbrs,offsets,perm,featsA,featsB,cg,region,edge_s,nb_s); break;
    case 1: eq_group_main<1>(a,t,lane,sh,rb,nbrs,offsets,perm,featsA,featsB,cg,region,edge_s,nb_s); break;
    case 2: eq_group_main<2>(a,t,lane,sh,rb,nbrs,offsets,perm,featsA,featsB,cg,region,edge_s,nb_s); break;
    case 3: eq_group_main<3>(a,t,lane,sh,rb,nbrs,offsets,perm,featsA,featsB,cg,region,edge_s,nb_s); break;
    case 4: eq_group_main<4>(a,t,lane,sh,rb,nbrs,offsets,perm,featsA,featsB,cg,region,edge_s,nb_s); break;
    case 5: eq_group_main<5>(a,t,lane,sh,rb,nbrs,offsets,perm,featsA,featsB,cg,region,edge_s,nb_s); break;
    case 6: eq_group_main<6>(a,t,lane,sh,rb,nbrs,offsets,perm,featsA,featsB,cg,region,edge_s,nb_s); break;
    default: eq_group_main<7>(a,t,lane,sh,rb,nbrs,offsets,perm,featsA,featsB,cg,region,edge_s,nb_s); break;
  }
}

// ---------------- energy readout (embed already folded into feats by k_tp) ----------------
__global__ __launch_bounds__(256) void k_energy(const float* __restrict__ feats,
    const float* __restrict__ wE, const float* __restrict__ bE,
    float* __restrict__ out, int N){
  const int wid = threadIdx.x >> 6, lane = threadIdx.x & 63;
  const int a = blockIdx.x*4 + wid;
  if(a >= N) return;
  float s = 0.f;
  for(int k=lane; k<256; k+=64) s += feats[(size_t)a*FTOT + k] * wE[k];
  #pragma unroll
  for(int off=32; off; off>>=1) s += __shfl_down(s, off, 64);
  if(lane == 0) out[a] = s + bE[0];
}

// ---------------- launcher ----------------
extern "C" void kernel_launch(void* const* d_in, const int* in_sizes, int n_in,
                              void* d_out, int out_size, void* d_ws, size_t ws_size,
                              hipStream_t stream){
  const float* sh        = (const float*)d_in[0];
  const float* rb        = (const float*)d_in[1];
  const float* emb_table = (const float*)d_in[2];
  const float* wE        = (const float*)d_in[3];
  const float* bE        = (const float*)d_in[4];
  const int*   species   = (const int*)d_in[5];
  const int*   centers   = (const int*)d_in[6];
  const int*   nbrs      = (const int*)d_in[7];
  const int N = in_sizes[5];
  const int P = in_sizes[6];

  char* ws = (char*)d_ws; size_t off = 0;
  auto carve = [&](size_t bytes)->void*{
    void* p = ws + off; off = (off + bytes + 255) & ~(size_t)255; return p;
  };
  float* cg_d    = (float*)carve((size_t)CGTOT*4);
  float* cemb    = (float*)carve((size_t)N*32*4);
  int*   counts  = (int*)  carve((size_t)N*4);
  int*   offsets = (int*)  carve((size_t)(N+1)*4);
  int*   cursor  = (int*)  carve((size_t)N*4);
  int*   perm    = (int*)  carve((size_t)P*4);
  float* featsA  = (float*)carve((size_t)N*FTOT*4);
  float* featsB  = (float*)carve((size_t)N*FTOT*4);
  (void)ws_size; (void)n_in; (void)out_size;

  static const std::vector<float> cg_host = build_cg();  // deterministic; host-side cache only
  hipMemcpyAsync(cg_d, cg_host.data(), (size_t)CGTOT*4, hipMemcpyHostToDevice, stream);

  k_cemb   <<<(N*32 + 255)/256, 256, 0, stream>>>(emb_table, species, cemb, counts, N);
  k_hist   <<<(P + 255)/256,    256, 0, stream>>>(centers, counts, P);
  k_scan   <<<1,                256, 0, stream>>>(counts, offsets, cursor, N);
  k_scatter<<<(P + 255)/256,    256, 0, stream>>>(centers, cursor, perm, P);
  k_inv    <<<N,                256, 0, stream>>>(sh, rb, cemb, nbrs, offsets, perm, featsA);
  k_tp     <<<N,                256, 0, stream>>>(featsA, cg_d, cemb);
  k_eq2    <<<N,                512, 0, stream>>>(sh, rb, nbrs, offsets, perm, featsA, featsB, cg_d);
  k_tp     <<<N,                256, 0, stream>>>(featsB, cg_d, cemb);
  k_energy <<<(N + 3)/4,        256, 0, stream>>>(featsB, wE, bE, (float*)d_out, N);
}